// Round 6
// baseline (1148.502 us; speedup 1.0000x reference)
//
#include <hip/hip_runtime.h>
#include <cstdint>

typedef unsigned long long u64;
typedef unsigned int u32;

#define CLS_T    0.05f
#define T0G      0.98f      // optimistic collect threshold (fast path)
#define TOPK     300
#define NWORDS   5          // ceil(300/64)
#define HBINS    2560
#define KEY_BASE 0x3D000000u
#define CCAP     1024
#define GCAP     8192       // per-class global candidate buffer

__device__ inline u32 bin_of_bits(u32 bits) {
    u32 b = (bits - KEY_BASE) >> 14;
    if (b > (HBINS - 1)) b = HBINS - 1;
    return b;
}

// compare-exchange for register bitonic: keep max if (lo==up), else min
__device__ inline void cex(u64& v, u64 p, bool lo, bool up) {
    u64 mx = v > p ? v : p;
    u64 mn = v > p ? p : v;
    v = (lo == up) ? mx : mn;
}
__device__ inline void sstep(u64& a0, u64& a1, u32 tid, u32 kk, u32 j) {
    u64 p0 = __shfl_xor((unsigned long long)a0, (int)j, 64);
    u64 p1 = __shfl_xor((unsigned long long)a1, (int)j, 64);
    bool lo = ((tid & j) == 0);
    cex(a0, p0, lo, ((tid & kk) == 0));
    cex(a1, p1, lo, (((tid + 512u) & kk) == 0));
}
__device__ inline void lstep(u64* cand, u64& a0, u64& a1, u32 tid, u32 kk, u32 j) {
    __syncthreads();
    cand[tid] = a0; cand[tid + 512] = a1;
    __syncthreads();
    u64 p0 = cand[tid ^ j], p1 = cand[(tid ^ j) + 512];
    bool lo = ((tid & j) == 0);
    cex(a0, p0, lo, ((tid & kk) == 0));
    cex(a1, p1, lo, (((tid + 512u) & kk) == 0));
}

// ---------------- decode boxes (+clip) + zero akey ----------------
__global__ void decode_kernel(const float* __restrict__ anc,
                              const float* __restrict__ reg,
                              const int* __restrict__ ph,
                              const int* __restrict__ pw,
                              float* __restrict__ boxes,
                              u64* __restrict__ akey, int A)
{
    int a = blockIdx.x * blockDim.x + threadIdx.x;
    if (a >= A) return;
    akey[a] = 0;
    float x1 = anc[a*4+0], y1 = anc[a*4+1], x2 = anc[a*4+2], y2 = anc[a*4+3];
    float w = x2 - x1, h = y2 - y1;
    float cx = x1 + 0.5f*w, cy = y1 + 0.5f*h;
    float r0 = reg[a*4+0]*0.1f, r1 = reg[a*4+1]*0.1f;
    float r2 = reg[a*4+2]*0.2f, r3 = reg[a*4+3]*0.2f;
    float pcx = cx + r0*w, pcy = cy + r1*h;
    float pw_ = expf(r2)*w, ph_ = expf(r3)*h;
    float W = (float)(*pw), H = (float)(*ph);
    boxes[a*4+0] = fmaxf(pcx - 0.5f*pw_, 0.0f);
    boxes[a*4+1] = fmaxf(pcy - 0.5f*ph_, 0.0f);
    boxes[a*4+2] = fminf(pcx + 0.5f*pw_, W);
    boxes[a*4+3] = fminf(pcy + 0.5f*ph_, H);
}

// ---------------- one coalesced pass: collect all (s > T0G) per class ----------------
// C hardcoded 80 (fast path only).
__global__ __launch_bounds__(256) void scan_collect_kernel(
    const float* __restrict__ cls, u32* __restrict__ gcnt,
    u64* __restrict__ gbuf, int A)
{
    size_t Nf4 = (size_t)A * 20;   // A*80/4
    size_t stride = (size_t)gridDim.x * 256;
    const float4* p4 = (const float4*)cls;
    for (size_t i = (size_t)blockIdx.x * 256 + threadIdx.x; i < Nf4; i += stride) {
        float4 v = p4[i];
        float ss[4] = {v.x, v.y, v.z, v.w};
        #pragma unroll
        for (int q = 0; q < 4; ++q) {
            if (ss[q] > T0G) {
                u32 flat = (u32)(i * 4 + q);
                u32 a = flat / 80u;            // const-div -> magic mul
                u32 c = flat - a * 80u;
                u32 pos = atomicAdd(&gcnt[c], 1u);
                if (pos < GCAP)
                    gbuf[(size_t)c * GCAP + pos] =
                        ((u64)__float_as_uint(ss[q]) << 32) | (u32)(~a);
            }
        }
    }
}

// ---------------- per-class: select top-300 + NMS + scatter (fused) ----------------
__global__ __launch_bounds__(512) void class_nms_fused_kernel(
    const u32* __restrict__ gcnt, const u64* __restrict__ gbuf,
    const float* __restrict__ cls,     // [A][C] for slow path
    const float* __restrict__ boxes, u64* __restrict__ akey, int A, int C)
{
    const int c = blockIdx.x;
    const u32 tid = threadIdx.x;
    const int lane = tid & 63;
    const int wv = tid >> 6;

    __shared__ u64 cand[CCAP];
    __shared__ u32 hist[HBINS];
    __shared__ u32 s_sel, s_cnt, s_rem;
    __shared__ float bx1[TOPK], by1[TOPK], bx2[TOPK], by2[TOPK], bar[TOPK];
    __shared__ u64 s_alive[NWORDS], s_newalive[NWORDS];
    __shared__ u32 s_changed;

    for (int i = tid; i < HBINS; i += 512) hist[i] = 0;
    if (tid == 0) { s_sel = 0; s_cnt = 0; s_changed = 0; }
    __syncthreads();

    const u32 n = gcnt[c];
    const bool fast = (n >= TOPK && n <= GCAP);
    u32 cnt_f;

    if (fast) {
        const u64* src = gbuf + (size_t)c * GCAP;
        // histogram of exact keys (16384-ulp bins)
        for (u32 i = tid; i < n; i += 512)
            atomicAdd(&hist[bin_of_bits((u32)(src[i] >> 32))], 1u);
        __syncthreads();
        // single-wave suffix scan for threshold bin
        if (tid < 64) {
            int base = HBINS - (lane + 1) * 40;
            u32 csum = 0;
            for (int q = 0; q < 40; ++q) csum += hist[base + q];
            u32 pref = csum;
            for (int d = 1; d < 64; d <<= 1) {
                u32 v = __shfl_up(pref, d);
                if (lane >= d) pref += v;
            }
            if (pref >= TOPK && (pref - csum) < TOPK) {
                u32 run = pref - csum;
                for (int q = 39; q >= 0; --q) {
                    run += hist[base + q];
                    if (run >= TOPK) { s_sel = (u32)(base + q); break; }
                }
            }
        }
        __syncthreads();
        const u32 thr = s_sel;
        // filter + wave-aggregated compaction
        for (u32 i = tid; i < n; i += 512) {
            u64 e = src[i];
            bool take = bin_of_bits((u32)(e >> 32)) >= thr;
            u64 m = __ballot(take);
            int nW = __popcll(m);
            if (nW) {
                int ldr = __ffsll((unsigned long long)m) - 1;
                u32 base2 = 0;
                if (lane == ldr) base2 = atomicAdd(&s_cnt, (u32)nW);
                base2 = __shfl(base2, ldr);
                if (take) {
                    u32 p = base2 + (u32)__popcll(m & ((1ull << lane) - 1ull));
                    if (p < CCAP) cand[p] = e;
                }
            }
        }
        __syncthreads();
        cnt_f = s_cnt < CCAP ? s_cnt : CCAP;
    } else {
        // ---- slow exact path: 2-level select over the class column ----
        for (int a = tid; a < A; a += 512) {
            float s = cls[(size_t)a * C + c];
            if (s > CLS_T) atomicAdd(&hist[bin_of_bits(__float_as_uint(s))], 1u);
        }
        __syncthreads();
        if (tid == 0) {
            u32 cum = 0; int sel = 0;
            for (int d = HBINS - 1; d >= 0; --d) {
                u32 nc = cum + hist[d];
                if (nc >= TOPK) { sel = d; break; }
                cum = nc;
            }
            s_sel = (u32)sel; s_rem = TOPK - cum;
        }
        __syncthreads();
        const u32 sel1 = s_sel;
        for (int i = tid; i < 256; i += 512) hist[i] = 0;
        __syncthreads();
        for (int a = tid; a < A; a += 512) {
            float s = cls[(size_t)a * C + c];
            if (s > CLS_T) {
                u32 k = __float_as_uint(s) - KEY_BASE;
                u32 b = k >> 14; if (b >= HBINS) b = HBINS - 1;
                if (b == sel1) atomicAdd(&hist[(k >> 6) & 0xFF], 1u);
            }
        }
        __syncthreads();
        if (tid == 0) {
            u32 rem = s_rem, cum = 0; int sel = 0;
            for (int d = 255; d >= 0; --d) {
                u32 nc = cum + hist[d];
                if (nc >= rem) { sel = d; break; }
                cum = nc;
            }
            s_sel = (sel1 << 14) | ((u32)sel << 6);
            s_cnt = 0;
        }
        __syncthreads();
        const u32 thresh = s_sel;
        for (int a = tid; a < A; a += 512) {
            float s = cls[(size_t)a * C + c];
            if (s > CLS_T) {
                u32 bits = __float_as_uint(s);
                if (bits - KEY_BASE >= thresh) {
                    u32 p = atomicAdd(&s_cnt, 1u);
                    if (p < CCAP) cand[p] = ((u64)bits << 32) | (u32)(~(u32)a);
                }
            }
        }
        __syncthreads();
        cnt_f = s_cnt < CCAP ? s_cnt : CCAP;
    }

    // ---- pad + register bitonic sort of 1024 (2 elems/thread), descending ----
    for (u32 i = cnt_f + tid; i < CCAP; i += 512) cand[i] = 0;
    __syncthreads();
    u64 a0 = cand[tid], a1 = cand[tid + 512];
    for (u32 kk = 2; kk <= 64; kk <<= 1)
        for (u32 j = kk >> 1; j >= 1; j >>= 1)
            sstep(a0, a1, tid, kk, j);
    lstep(cand, a0, a1, tid, 128u, 64u);
    for (u32 j = 32; j >= 1; j >>= 1) sstep(a0, a1, tid, 128u, j);
    lstep(cand, a0, a1, tid, 256u, 128u);
    lstep(cand, a0, a1, tid, 256u, 64u);
    for (u32 j = 32; j >= 1; j >>= 1) sstep(a0, a1, tid, 256u, j);
    lstep(cand, a0, a1, tid, 512u, 256u);
    lstep(cand, a0, a1, tid, 512u, 128u);
    lstep(cand, a0, a1, tid, 512u, 64u);
    for (u32 j = 32; j >= 1; j >>= 1) sstep(a0, a1, tid, 512u, j);
    {   // kk=1024, j=512: in-thread exchange (up = true for tid<512)
        u64 mx = a0 > a1 ? a0 : a1, mn = a0 > a1 ? a1 : a0;
        a0 = mx; a1 = mn;
    }
    lstep(cand, a0, a1, tid, 1024u, 256u);
    lstep(cand, a0, a1, tid, 1024u, 128u);
    lstep(cand, a0, a1, tid, 1024u, 64u);
    for (u32 j = 32; j >= 1; j >>= 1) sstep(a0, a1, tid, 1024u, j);
    // thread tid holds sorted element tid in a0

    const int T = (int)(cnt_f < TOPK ? cnt_f : TOPK);

    // ---- boxes for my candidate ----
    u64 key = a0; u32 aidx = 0;
    float x1 = 0, y1 = 0, x2 = 0, y2 = 0, ar = 0;
    if ((int)tid < T) {
        aidx = ~(u32)(key & 0xFFFFFFFFull);
        float4 b4 = *(const float4*)(boxes + (size_t)aidx * 4);
        x1 = b4.x; y1 = b4.y; x2 = b4.z; y2 = b4.w;
        ar = fmaxf(x2 - x1, 0.0f) * fmaxf(y2 - y1, 0.0f);
        bx1[tid] = x1; by1[tid] = y1; bx2[tid] = x2; by2[tid] = y2; bar[tid] = ar;
    }
    if (tid < NWORDS) {
        int rem = T - (int)tid * 64;
        s_alive[tid] = rem >= 64 ? ~0ull : (rem > 0 ? ((1ull << rem) - 1ull) : 0ull);
    }
    __syncthreads();

    // colmask: which i<tid suppress me (IoU>0.5), in registers
    u64 cm[NWORDS] = {0,0,0,0,0};
    if ((int)tid < T) {
        for (int i = 0; i < (int)tid; ++i) {
            float iw = fmaxf(fminf(x2, bx2[i]) - fmaxf(x1, bx1[i]), 0.0f);
            float ih = fmaxf(fminf(y2, by2[i]) - fmaxf(y1, by1[i]), 0.0f);
            float inter = iw * ih;
            float uni = ((ar + bar[i]) - inter) + 1e-8f;
            float q = inter - 0.5f * uni;
            bool sup;
            if (fabsf(q) > 1e-5f * uni) sup = (q > 0.0f);
            else sup = (inter / uni > 0.5f);
            if (sup) cm[i >> 6] |= 1ull << (i & 63);
        }
    }

    // synchronous fixpoint == greedy keep set
    for (int round = 0; round < TOPK; ++round) {
        u64 al[NWORDS];
        #pragma unroll
        for (int k2 = 0; k2 < NWORDS; ++k2) al[k2] = s_alive[k2];
        bool alive_t = false;
        if ((int)tid < T) {
            u64 any = 0;
            #pragma unroll
            for (int k2 = 0; k2 < NWORDS; ++k2) any |= (al[k2] & cm[k2]);
            alive_t = (any == 0);
        }
        u64 w = __ballot(alive_t);
        if (wv < NWORDS && lane == 0) {
            s_newalive[wv] = w;
            if (w != al[wv]) s_changed = 1;
        }
        __syncthreads();
        u32 ch = s_changed;
        __syncthreads();
        if (!ch) break;
        if (tid < NWORDS) s_alive[tid] = s_newalive[tid];
        if (tid == 0) s_changed = 0;
        __syncthreads();
    }

    if ((int)tid < T) {
        if ((s_alive[tid >> 6] >> (tid & 63)) & 1ull) {
            u32 sbits = (u32)(key >> 32);
            u64 outk = ((u64)sbits << 32) | (u32)(255 - c);
            atomicMax(&akey[aidx], outk);
        }
    }
}

// ---------------- finalize ----------------
__global__ void finalize_kernel(const u64* __restrict__ akey,
                                float* __restrict__ out, int A)
{
    int a = blockIdx.x * blockDim.x + threadIdx.x;
    if (a >= A) return;
    float* scores = out;
    float* labels = out + A;
    float* boxes  = out + (size_t)2 * A;
    u64 k = akey[a];
    if (k) {
        scores[a] = __uint_as_float((u32)(k >> 32));
        labels[a] = (float)(int)(255u - (u32)(k & 0xFFFFFFFFull));
    } else {
        scores[a] = 0.0f;
        labels[a] = -1.0f;
        boxes[(size_t)a*4+0] = 0.0f;
        boxes[(size_t)a*4+1] = 0.0f;
        boxes[(size_t)a*4+2] = 0.0f;
        boxes[(size_t)a*4+3] = 0.0f;
    }
}

// ---------------- fallback (generic C / small ws): round-1 proven kernel ----------------
#define FB_CAP 1024
__global__ __launch_bounds__(256) void fb_topk_nms_kernel(
    const float* __restrict__ cls,
    const float* __restrict__ boxes,
    u64* __restrict__ akey,
    int A, int C)
{
    const int c   = blockIdx.x;
    const int tid = threadIdx.x;

    __shared__ u32 hist[HBINS];
    __shared__ u64 cand[FB_CAP];
    __shared__ float bx1[TOPK], by1[TOPK], bx2[TOPK], by2[TOPK], bar[TOPK];
    __shared__ u64 iomask[TOPK][NWORDS];
    __shared__ u64 keepm[NWORDS];
    __shared__ u32 s_sel1, s_sel2, s_rem, s_cnt;

    for (int i = tid; i < HBINS; i += 256) hist[i] = 0;
    __syncthreads();
    for (int a = tid; a < A; a += 256) {
        float s = cls[(size_t)a * C + c];
        if (s > CLS_T) {
            u32 k = __float_as_uint(s) - KEY_BASE;
            u32 b = k >> 14; if (b >= HBINS) b = HBINS - 1;
            atomicAdd(&hist[b], 1u);
        }
    }
    __syncthreads();
    if (tid == 0) {
        u32 cum = 0; int sel = 0;
        for (int d = HBINS - 1; d >= 0; --d) {
            u32 nc = cum + hist[d];
            if (nc >= TOPK) { sel = d; break; }
            cum = nc;
        }
        s_sel1 = (u32)sel; s_rem = TOPK - cum;
    }
    __syncthreads();
    const u32 sel1 = s_sel1;

    for (int i = tid; i < 256; i += 256) hist[i] = 0;
    __syncthreads();
    for (int a = tid; a < A; a += 256) {
        float s = cls[(size_t)a * C + c];
        if (s > CLS_T) {
            u32 k = __float_as_uint(s) - KEY_BASE;
            u32 b = k >> 14; if (b >= HBINS) b = HBINS - 1;
            if (b == sel1) atomicAdd(&hist[(k >> 6) & 0xFF], 1u);
        }
    }
    __syncthreads();
    if (tid == 0) {
        u32 rem = s_rem, cum = 0; int sel = 0;
        for (int d = 255; d >= 0; --d) {
            u32 nc = cum + hist[d];
            if (nc >= rem) { sel = d; break; }
            cum = nc;
        }
        s_sel2 = (u32)sel; s_cnt = 0;
    }
    __syncthreads();
    const u32 thresh = (sel1 << 14) | (s_sel2 << 6);

    for (int a = tid; a < A; a += 256) {
        float s = cls[(size_t)a * C + c];
        if (s > CLS_T) {
            u32 bits = __float_as_uint(s);
            u32 k = bits - KEY_BASE;
            if (k >= thresh) {
                u32 pos = atomicAdd(&s_cnt, 1u);
                if (pos < FB_CAP) cand[pos] = ((u64)bits << 32) | (u32)(~(u32)a);
            }
        }
    }
    __syncthreads();
    const u32 total = s_cnt < FB_CAP ? s_cnt : FB_CAP;
    for (int i = tid; i < FB_CAP; i += 256)
        if (i >= (int)total) cand[i] = 0;
    __syncthreads();

    for (u32 kk = 2; kk <= FB_CAP; kk <<= 1) {
        for (u32 j = kk >> 1; j > 0; j >>= 1) {
            for (u32 i = tid; i < FB_CAP; i += 256) {
                u32 l = i ^ j;
                if (l > i) {
                    u64 av = cand[i], bv = cand[l];
                    bool up = ((i & kk) == 0);
                    if ((up && av < bv) || (!up && av > bv)) { cand[i] = bv; cand[l] = av; }
                }
            }
            __syncthreads();
        }
    }
    const int T = (int)(total < TOPK ? total : TOPK);

    for (int i = tid; i < T; i += 256) {
        u32 a = ~(u32)(cand[i] & 0xFFFFFFFFull);
        float x1 = boxes[(size_t)a*4+0], y1 = boxes[(size_t)a*4+1];
        float x2 = boxes[(size_t)a*4+2], y2 = boxes[(size_t)a*4+3];
        bx1[i] = x1; by1[i] = y1; bx2[i] = x2; by2[i] = y2;
        bar[i] = fmaxf(x2 - x1, 0.0f) * fmaxf(y2 - y1, 0.0f);
    }
    __syncthreads();

    for (int i = tid; i < T; i += 256) {
        u64 m[NWORDS] = {0,0,0,0,0};
        float x1 = bx1[i], y1 = by1[i], x2 = bx2[i], y2 = by2[i], ai = bar[i];
        for (int j = i + 1; j < T; ++j) {
            float iw = fmaxf(fminf(x2, bx2[j]) - fmaxf(x1, bx1[j]), 0.0f);
            float ih = fmaxf(fminf(y2, by2[j]) - fmaxf(y1, by1[j]), 0.0f);
            float inter = iw * ih;
            float uni = ((ai + bar[j]) - inter) + 1e-8f;
            if (inter / uni > 0.5f) m[j >> 6] |= 1ull << (j & 63);
        }
        for (int k2 = 0; k2 < NWORDS; ++k2) iomask[i][k2] = m[k2];
    }
    __syncthreads();

    if (tid == 0) {
        u64 sup[NWORDS] = {0,0,0,0,0};
        u64 kp [NWORDS] = {0,0,0,0,0};
        for (int i = 0; i < T; ++i) {
            if (!((sup[i >> 6] >> (i & 63)) & 1ull)) {
                kp[i >> 6] |= 1ull << (i & 63);
                for (int k2 = 0; k2 < NWORDS; ++k2) sup[k2] |= iomask[i][k2];
            }
        }
        for (int k2 = 0; k2 < NWORDS; ++k2) keepm[k2] = kp[k2];
    }
    __syncthreads();

    for (int i = tid; i < T; i += 256) {
        if ((keepm[i >> 6] >> (i & 63)) & 1ull) {
            u64 key = cand[i];
            u32 a = ~(u32)(key & 0xFFFFFFFFull);
            u32 sbits = (u32)(key >> 32);
            u64 outk = ((u64)sbits << 32) | (u32)(255 - c);
            atomicMax(&akey[a], outk);
        }
    }
}

extern "C" void kernel_launch(void* const* d_in, const int* in_sizes, int n_in,
                              void* d_out, int out_size, void* d_ws, size_t ws_size,
                              hipStream_t stream) {
    const float* cls = (const float*)d_in[0];
    const float* reg = (const float*)d_in[1];
    const float* anc = (const float*)d_in[2];
    const int*   ph  = (const int*)d_in[3];
    const int*   pw  = (const int*)d_in[4];

    int A = in_sizes[2] / 4;
    int C = in_sizes[0] / A;

    float* out       = (float*)d_out;
    float* out_boxes = out + (size_t)2 * A;

    // workspace layout: akey | gcnt | gbuf
    size_t akey_bytes = (size_t)A * sizeof(u64);
    size_t off_gc     = (akey_bytes + 255) & ~(size_t)255;
    size_t gc_bytes   = 80 * sizeof(u32);
    size_t off_gb     = (off_gc + gc_bytes + 255) & ~(size_t)255;
    size_t gb_bytes   = (size_t)80 * GCAP * sizeof(u64);
    size_t need       = off_gb + gb_bytes;

    u64* akey = (u64*)d_ws;

    decode_kernel<<<(A + 255) / 256, 256, 0, stream>>>(anc, reg, ph, pw, out_boxes, akey, A);

    bool fastpath = (C == 80) && ((A & 3) == 0) && (A < (1 << 20)) && (ws_size >= need);
    if (fastpath) {
        u32* gcnt = (u32*)((char*)d_ws + off_gc);
        u64* gbuf = (u64*)((char*)d_ws + off_gb);

        hipMemsetAsync(gcnt, 0, gc_bytes, stream);
        size_t Nf4 = (size_t)A * 20;
        int blocks = (int)((Nf4 + 255) / 256);
        if (blocks > 4096) blocks = 4096;
        scan_collect_kernel<<<blocks, 256, 0, stream>>>(cls, gcnt, gbuf, A);
        class_nms_fused_kernel<<<C, 512, 0, stream>>>(gcnt, gbuf, cls, out_boxes, akey, A, C);
    } else {
        fb_topk_nms_kernel<<<C, 256, 0, stream>>>(cls, out_boxes, akey, A, C);
    }

    finalize_kernel<<<(A + 255) / 256, 256, 0, stream>>>(akey, out, A);
}

// Round 7
// 176.572 us; speedup vs baseline: 6.5045x; 6.5045x over previous
//
#include <hip/hip_runtime.h>
#include <cstdint>

typedef unsigned long long u64;
typedef unsigned int u32;

#define CLS_T    0.05f
#define T0G      0.98f      // collect threshold (pass 1)
#define T1G      0.9965f    // candidate filter threshold (pass 2)
#define TOPK     300
#define NWORDS   5          // ceil(300/64)
#define HBINS    2560
#define KEY_BASE 0x3D000000u
#define CCAP     1024
#define NBLK     2048       // scan blocks
#define SCAP     24         // slots per (class, scan-block)

__device__ inline u32 bin_of_bits(u32 bits) {
    u32 b = (bits - KEY_BASE) >> 14;
    if (b > (HBINS - 1)) b = HBINS - 1;
    return b;
}

// compare-exchange for register bitonic: keep max if (lo==up), else min
__device__ inline void cex(u64& v, u64 p, bool lo, bool up) {
    u64 mx = v > p ? v : p;
    u64 mn = v > p ? p : v;
    v = (lo == up) ? mx : mn;
}
__device__ inline void sstep(u64& a0, u64& a1, u32 tid, u32 kk, u32 j) {
    u64 p0 = __shfl_xor((unsigned long long)a0, (int)j, 64);
    u64 p1 = __shfl_xor((unsigned long long)a1, (int)j, 64);
    bool lo = ((tid & j) == 0);
    cex(a0, p0, lo, ((tid & kk) == 0));
    cex(a1, p1, lo, (((tid + 512u) & kk) == 0));
}
__device__ inline void lstep(u64* cand, u64& a0, u64& a1, u32 tid, u32 kk, u32 j) {
    __syncthreads();
    cand[tid] = a0; cand[tid + 512] = a1;
    __syncthreads();
    u64 p0 = cand[tid ^ j], p1 = cand[(tid ^ j) + 512];
    bool lo = ((tid & j) == 0);
    cex(a0, p0, lo, ((tid & kk) == 0));
    cex(a1, p1, lo, (((tid + 512u) & kk) == 0));
}

// ---------------- decode boxes (+clip) + zero akey ----------------
__global__ void decode_kernel(const float* __restrict__ anc,
                              const float* __restrict__ reg,
                              const int* __restrict__ ph,
                              const int* __restrict__ pw,
                              float* __restrict__ boxes,
                              u64* __restrict__ akey, int A)
{
    int a = blockIdx.x * blockDim.x + threadIdx.x;
    if (a >= A) return;
    akey[a] = 0;
    float x1 = anc[a*4+0], y1 = anc[a*4+1], x2 = anc[a*4+2], y2 = anc[a*4+3];
    float w = x2 - x1, h = y2 - y1;
    float cx = x1 + 0.5f*w, cy = y1 + 0.5f*h;
    float r0 = reg[a*4+0]*0.1f, r1 = reg[a*4+1]*0.1f;
    float r2 = reg[a*4+2]*0.2f, r3 = reg[a*4+3]*0.2f;
    float pcx = cx + r0*w, pcy = cy + r1*h;
    float pw_ = expf(r2)*w, ph_ = expf(r3)*h;
    float W = (float)(*pw), H = (float)(*ph);
    boxes[a*4+0] = fmaxf(pcx - 0.5f*pw_, 0.0f);
    boxes[a*4+1] = fmaxf(pcy - 0.5f*ph_, 0.0f);
    boxes[a*4+2] = fminf(pcx + 0.5f*pw_, W);
    boxes[a*4+3] = fminf(pcy + 0.5f*ph_, H);
}

// ---------------- one coalesced pass: collect s > T0G, zero global atomics ----------------
// C hardcoded 80 (fast path only). Each block owns private (class,block) regions.
__global__ __launch_bounds__(256) void scan_collect_kernel(
    const float* __restrict__ cls,
    u64* __restrict__ gbuf, u32* __restrict__ segcnt,
    u32* __restrict__ overflow, int A)
{
    __shared__ u32 cnt[80];
    __shared__ u64 buf[80][SCAP];
    __shared__ u32 s_over;
    const int tid = threadIdx.x;
    const int blk = blockIdx.x;

    for (int i = tid; i < 80; i += 256) cnt[i] = 0;
    if (tid == 0) s_over = 0;
    __syncthreads();

    size_t Nf4 = (size_t)A * 20;   // A*80/4
    const float4* p4 = (const float4*)cls;
    for (size_t i = (size_t)blk * 256 + tid; i < Nf4; i += (size_t)NBLK * 256) {
        float4 v = p4[i];
        float ss[4] = {v.x, v.y, v.z, v.w};
        #pragma unroll
        for (int q = 0; q < 4; ++q) {
            if (ss[q] > T0G) {
                u32 flat = (u32)(i * 4 + q);
                u32 a = flat / 80u;            // const-div -> magic mul
                u32 c = flat - a * 80u;
                u32 p = atomicAdd(&cnt[c], 1u);   // LDS atomic only
                if (p < SCAP) buf[c][p] = ((u64)__float_as_uint(ss[q]) << 32) | (u32)(~a);
                else s_over = 1;
            }
        }
    }
    __syncthreads();

    // flush: private regions, plain stores
    for (int m = tid; m < 80 * SCAP; m += 256) {
        int c = m / SCAP, e = m - c * SCAP;
        u32 cc = cnt[c]; if (cc > SCAP) cc = SCAP;
        if ((u32)e < cc)
            gbuf[((size_t)c * NBLK + blk) * SCAP + e] = buf[c][e];
    }
    for (int c = tid; c < 80; c += 256) {
        u32 cc = cnt[c]; if (cc > SCAP) cc = SCAP;
        segcnt[(size_t)c * NBLK + blk] = cc;
    }
    if (tid == 0 && s_over) *overflow = 1;
}

// ---------------- per-class: gather + sort + NMS + scatter (fused) ----------------
__global__ __launch_bounds__(512) void class_nms_fused_kernel(
    const u32* __restrict__ segcnt, const u64* __restrict__ gbuf,
    const u32* __restrict__ overflow,
    const float* __restrict__ cls,     // [A][C] for slow path
    const float* __restrict__ boxes, u64* __restrict__ akey, int A, int C)
{
    const int c = blockIdx.x;
    const u32 tid = threadIdx.x;
    const int lane = tid & 63;
    const int wv = tid >> 6;

    __shared__ u32 sh[HBINS];          // fast: scnt[0..NBLK); slow: hist[0..HBINS)
    __shared__ u64 cand[CCAP];
    __shared__ u32 s_sel, s_cnt, s_rem;
    __shared__ float bx1[TOPK], by1[TOPK], bx2[TOPK], by2[TOPK], bar[TOPK];
    __shared__ u64 s_alive[NWORDS], s_newalive[NWORDS];
    __shared__ u32 s_changed;

    if (tid == 0) { s_sel = 0; s_cnt = 0; s_changed = 0; }
    __syncthreads();

    const bool over = (*overflow != 0);
    u32 cnt_f = 0;
    bool fast_ok = false;

    if (!over) {
        // stage per-block counts for this class
        for (int i = tid; i < NBLK; i += 512) sh[i] = segcnt[(size_t)c * NBLK + i];
        __syncthreads();
        const u32 T1 = __float_as_uint(T1G);
        // wave-per-segment gather, filter s > T1, ballot compaction
        for (int b = wv; b < NBLK; b += 8) {
            u32 cb = sh[b];
            u64 e = 0; bool take = false;
            if ((u32)lane < cb) {
                e = gbuf[((size_t)c * NBLK + b) * SCAP + lane];
                take = ((u32)(e >> 32) > T1);
            }
            u64 m = __ballot(take);
            int nW = __popcll(m);
            if (nW) {
                int ldr = __ffsll((unsigned long long)m) - 1;
                u32 base = 0;
                if (lane == ldr) base = atomicAdd(&s_cnt, (u32)nW);
                base = __shfl(base, ldr);
                if (take) {
                    u32 p = base + (u32)__popcll(m & ((1ull << lane) - 1ull));
                    if (p < CCAP) cand[p] = e;
                }
            }
        }
        __syncthreads();
        cnt_f = s_cnt;
        fast_ok = (cnt_f >= TOPK && cnt_f <= CCAP);
    }

    if (!fast_ok) {
        // ---- slow exact path: 2-level select over the class column ----
        __syncthreads();
        for (int i = tid; i < HBINS; i += 512) sh[i] = 0;
        if (tid == 0) s_cnt = 0;
        __syncthreads();
        for (int a = tid; a < A; a += 512) {
            float s = cls[(size_t)a * C + c];
            if (s > CLS_T) atomicAdd(&sh[bin_of_bits(__float_as_uint(s))], 1u);
        }
        __syncthreads();
        if (tid == 0) {
            u32 cum = 0; int sel = 0;
            for (int d = HBINS - 1; d >= 0; --d) {
                u32 nc = cum + sh[d];
                if (nc >= TOPK) { sel = d; break; }
                cum = nc;
            }
            s_sel = (u32)sel; s_rem = TOPK - cum;
        }
        __syncthreads();
        const u32 sel1 = s_sel;
        __syncthreads();
        for (int i = tid; i < 256; i += 512) sh[i] = 0;
        __syncthreads();
        for (int a = tid; a < A; a += 512) {
            float s = cls[(size_t)a * C + c];
            if (s > CLS_T) {
                u32 k = __float_as_uint(s) - KEY_BASE;
                u32 b = k >> 14; if (b >= HBINS) b = HBINS - 1;
                if (b == sel1) atomicAdd(&sh[(k >> 6) & 0xFF], 1u);
            }
        }
        __syncthreads();
        if (tid == 0) {
            u32 rem = s_rem, cum = 0; int sel = 0;
            for (int d = 255; d >= 0; --d) {
                u32 nc = cum + sh[d];
                if (nc >= rem) { sel = d; break; }
                cum = nc;
            }
            s_sel = (sel1 << 14) | ((u32)sel << 6);
            s_cnt = 0;
        }
        __syncthreads();
        const u32 thresh = s_sel;
        for (int a = tid; a < A; a += 512) {
            float s = cls[(size_t)a * C + c];
            if (s > CLS_T) {
                u32 bits = __float_as_uint(s);
                if (bits - KEY_BASE >= thresh) {
                    u32 p = atomicAdd(&s_cnt, 1u);
                    if (p < CCAP) cand[p] = ((u64)bits << 32) | (u32)(~(u32)a);
                }
            }
        }
        __syncthreads();
        cnt_f = s_cnt < CCAP ? s_cnt : CCAP;
    }

    // ---- pad + register bitonic sort of 1024 (2 elems/thread), descending ----
    for (u32 i = cnt_f + tid; i < CCAP; i += 512) cand[i] = 0;
    __syncthreads();
    u64 a0 = cand[tid], a1 = cand[tid + 512];
    for (u32 kk = 2; kk <= 64; kk <<= 1)
        for (u32 j = kk >> 1; j >= 1; j >>= 1)
            sstep(a0, a1, tid, kk, j);
    lstep(cand, a0, a1, tid, 128u, 64u);
    for (u32 j = 32; j >= 1; j >>= 1) sstep(a0, a1, tid, 128u, j);
    lstep(cand, a0, a1, tid, 256u, 128u);
    lstep(cand, a0, a1, tid, 256u, 64u);
    for (u32 j = 32; j >= 1; j >>= 1) sstep(a0, a1, tid, 256u, j);
    lstep(cand, a0, a1, tid, 512u, 256u);
    lstep(cand, a0, a1, tid, 512u, 128u);
    lstep(cand, a0, a1, tid, 512u, 64u);
    for (u32 j = 32; j >= 1; j >>= 1) sstep(a0, a1, tid, 512u, j);
    {   // kk=1024, j=512: in-thread exchange (up = true for tid<512)
        u64 mx = a0 > a1 ? a0 : a1, mn = a0 > a1 ? a1 : a0;
        a0 = mx; a1 = mn;
    }
    lstep(cand, a0, a1, tid, 1024u, 256u);
    lstep(cand, a0, a1, tid, 1024u, 128u);
    lstep(cand, a0, a1, tid, 1024u, 64u);
    for (u32 j = 32; j >= 1; j >>= 1) sstep(a0, a1, tid, 1024u, j);
    // thread tid holds sorted element tid in a0

    const int T = (int)(cnt_f < TOPK ? cnt_f : TOPK);

    // ---- boxes for my candidate ----
    u64 key = a0; u32 aidx = 0;
    float x1 = 0, y1 = 0, x2 = 0, y2 = 0, ar = 0;
    if ((int)tid < T) {
        aidx = ~(u32)(key & 0xFFFFFFFFull);
        float4 b4 = *(const float4*)(boxes + (size_t)aidx * 4);
        x1 = b4.x; y1 = b4.y; x2 = b4.z; y2 = b4.w;
        ar = fmaxf(x2 - x1, 0.0f) * fmaxf(y2 - y1, 0.0f);
        bx1[tid] = x1; by1[tid] = y1; bx2[tid] = x2; by2[tid] = y2; bar[tid] = ar;
    }
    if (tid < NWORDS) {
        int rem = T - (int)tid * 64;
        s_alive[tid] = rem >= 64 ? ~0ull : (rem > 0 ? ((1ull << rem) - 1ull) : 0ull);
    }
    __syncthreads();

    // colmask: which i<tid suppress me (IoU>0.5), in registers
    u64 cm[NWORDS] = {0,0,0,0,0};
    if ((int)tid < T) {
        for (int i = 0; i < (int)tid; ++i) {
            float iw = fmaxf(fminf(x2, bx2[i]) - fmaxf(x1, bx1[i]), 0.0f);
            float ih = fmaxf(fminf(y2, by2[i]) - fmaxf(y1, by1[i]), 0.0f);
            float inter = iw * ih;
            float uni = ((ar + bar[i]) - inter) + 1e-8f;
            float q = inter - 0.5f * uni;
            bool sup;
            if (fabsf(q) > 1e-5f * uni) sup = (q > 0.0f);
            else sup = (inter / uni > 0.5f);
            if (sup) cm[i >> 6] |= 1ull << (i & 63);
        }
    }

    // synchronous fixpoint == greedy keep set
    for (int round = 0; round < TOPK; ++round) {
        u64 al[NWORDS];
        #pragma unroll
        for (int k2 = 0; k2 < NWORDS; ++k2) al[k2] = s_alive[k2];
        bool alive_t = false;
        if ((int)tid < T) {
            u64 any = 0;
            #pragma unroll
            for (int k2 = 0; k2 < NWORDS; ++k2) any |= (al[k2] & cm[k2]);
            alive_t = (any == 0);
        }
        u64 w = __ballot(alive_t);
        if (wv < NWORDS && lane == 0) {
            s_newalive[wv] = w;
            if (w != al[wv]) s_changed = 1;
        }
        __syncthreads();
        u32 ch = s_changed;
        __syncthreads();
        if (!ch) break;
        if (tid < NWORDS) s_alive[tid] = s_newalive[tid];
        if (tid == 0) s_changed = 0;
        __syncthreads();
    }

    if ((int)tid < T) {
        if ((s_alive[tid >> 6] >> (tid & 63)) & 1ull) {
            u32 sbits = (u32)(key >> 32);
            u64 outk = ((u64)sbits << 32) | (u32)(255 - c);
            atomicMax(&akey[aidx], outk);
        }
    }
}

// ---------------- finalize ----------------
__global__ void finalize_kernel(const u64* __restrict__ akey,
                                float* __restrict__ out, int A)
{
    int a = blockIdx.x * blockDim.x + threadIdx.x;
    if (a >= A) return;
    float* scores = out;
    float* labels = out + A;
    float* boxes  = out + (size_t)2 * A;
    u64 k = akey[a];
    if (k) {
        scores[a] = __uint_as_float((u32)(k >> 32));
        labels[a] = (float)(int)(255u - (u32)(k & 0xFFFFFFFFull));
    } else {
        scores[a] = 0.0f;
        labels[a] = -1.0f;
        boxes[(size_t)a*4+0] = 0.0f;
        boxes[(size_t)a*4+1] = 0.0f;
        boxes[(size_t)a*4+2] = 0.0f;
        boxes[(size_t)a*4+3] = 0.0f;
    }
}

// ---------------- fallback (generic C / small ws): round-1 proven kernel ----------------
#define FB_CAP 1024
__global__ __launch_bounds__(256) void fb_topk_nms_kernel(
    const float* __restrict__ cls,
    const float* __restrict__ boxes,
    u64* __restrict__ akey,
    int A, int C)
{
    const int c   = blockIdx.x;
    const int tid = threadIdx.x;

    __shared__ u32 hist[HBINS];
    __shared__ u64 cand[FB_CAP];
    __shared__ float bx1[TOPK], by1[TOPK], bx2[TOPK], by2[TOPK], bar[TOPK];
    __shared__ u64 iomask[TOPK][NWORDS];
    __shared__ u64 keepm[NWORDS];
    __shared__ u32 s_sel1, s_sel2, s_rem, s_cnt;

    for (int i = tid; i < HBINS; i += 256) hist[i] = 0;
    __syncthreads();
    for (int a = tid; a < A; a += 256) {
        float s = cls[(size_t)a * C + c];
        if (s > CLS_T) {
            u32 k = __float_as_uint(s) - KEY_BASE;
            u32 b = k >> 14; if (b >= HBINS) b = HBINS - 1;
            atomicAdd(&hist[b], 1u);
        }
    }
    __syncthreads();
    if (tid == 0) {
        u32 cum = 0; int sel = 0;
        for (int d = HBINS - 1; d >= 0; --d) {
            u32 nc = cum + hist[d];
            if (nc >= TOPK) { sel = d; break; }
            cum = nc;
        }
        s_sel1 = (u32)sel; s_rem = TOPK - cum;
    }
    __syncthreads();
    const u32 sel1 = s_sel1;

    for (int i = tid; i < 256; i += 256) hist[i] = 0;
    __syncthreads();
    for (int a = tid; a < A; a += 256) {
        float s = cls[(size_t)a * C + c];
        if (s > CLS_T) {
            u32 k = __float_as_uint(s) - KEY_BASE;
            u32 b = k >> 14; if (b >= HBINS) b = HBINS - 1;
            if (b == sel1) atomicAdd(&hist[(k >> 6) & 0xFF], 1u);
        }
    }
    __syncthreads();
    if (tid == 0) {
        u32 rem = s_rem, cum = 0; int sel = 0;
        for (int d = 255; d >= 0; --d) {
            u32 nc = cum + hist[d];
            if (nc >= rem) { sel = d; break; }
            cum = nc;
        }
        s_sel2 = (u32)sel; s_cnt = 0;
    }
    __syncthreads();
    const u32 thresh = (sel1 << 14) | (s_sel2 << 6);

    for (int a = tid; a < A; a += 256) {
        float s = cls[(size_t)a * C + c];
        if (s > CLS_T) {
            u32 bits = __float_as_uint(s);
            u32 k = bits - KEY_BASE;
            if (k >= thresh) {
                u32 pos = atomicAdd(&s_cnt, 1u);
                if (pos < FB_CAP) cand[pos] = ((u64)bits << 32) | (u32)(~(u32)a);
            }
        }
    }
    __syncthreads();
    const u32 total = s_cnt < FB_CAP ? s_cnt : FB_CAP;
    for (int i = tid; i < FB_CAP; i += 256)
        if (i >= (int)total) cand[i] = 0;
    __syncthreads();

    for (u32 kk = 2; kk <= FB_CAP; kk <<= 1) {
        for (u32 j = kk >> 1; j > 0; j >>= 1) {
            for (u32 i = tid; i < FB_CAP; i += 256) {
                u32 l = i ^ j;
                if (l > i) {
                    u64 av = cand[i], bv = cand[l];
                    bool up = ((i & kk) == 0);
                    if ((up && av < bv) || (!up && av > bv)) { cand[i] = bv; cand[l] = av; }
                }
            }
            __syncthreads();
        }
    }
    const int T = (int)(total < TOPK ? total : TOPK);

    for (int i = tid; i < T; i += 256) {
        u32 a = ~(u32)(cand[i] & 0xFFFFFFFFull);
        float x1 = boxes[(size_t)a*4+0], y1 = boxes[(size_t)a*4+1];
        float x2 = boxes[(size_t)a*4+2], y2 = boxes[(size_t)a*4+3];
        bx1[i] = x1; by1[i] = y1; bx2[i] = x2; by2[i] = y2;
        bar[i] = fmaxf(x2 - x1, 0.0f) * fmaxf(y2 - y1, 0.0f);
    }
    __syncthreads();

    for (int i = tid; i < T; i += 256) {
        u64 m[NWORDS] = {0,0,0,0,0};
        float x1 = bx1[i], y1 = by1[i], x2 = bx2[i], y2 = by2[i], ai = bar[i];
        for (int j = i + 1; j < T; ++j) {
            float iw = fmaxf(fminf(x2, bx2[j]) - fmaxf(x1, bx1[j]), 0.0f);
            float ih = fmaxf(fminf(y2, by2[j]) - fmaxf(y1, by1[j]), 0.0f);
            float inter = iw * ih;
            float uni = ((ai + bar[j]) - inter) + 1e-8f;
            if (inter / uni > 0.5f) m[j >> 6] |= 1ull << (j & 63);
        }
        for (int k2 = 0; k2 < NWORDS; ++k2) iomask[i][k2] = m[k2];
    }
    __syncthreads();

    if (tid == 0) {
        u64 sup[NWORDS] = {0,0,0,0,0};
        u64 kp [NWORDS] = {0,0,0,0,0};
        for (int i = 0; i < T; ++i) {
            if (!((sup[i >> 6] >> (i & 63)) & 1ull)) {
                kp[i >> 6] |= 1ull << (i & 63);
                for (int k2 = 0; k2 < NWORDS; ++k2) sup[k2] |= iomask[i][k2];
            }
        }
        for (int k2 = 0; k2 < NWORDS; ++k2) keepm[k2] = kp[k2];
    }
    __syncthreads();

    for (int i = tid; i < T; i += 256) {
        if ((keepm[i >> 6] >> (i & 63)) & 1ull) {
            u64 key = cand[i];
            u32 a = ~(u32)(key & 0xFFFFFFFFull);
            u32 sbits = (u32)(key >> 32);
            u64 outk = ((u64)sbits << 32) | (u32)(255 - c);
            atomicMax(&akey[a], outk);
        }
    }
}

extern "C" void kernel_launch(void* const* d_in, const int* in_sizes, int n_in,
                              void* d_out, int out_size, void* d_ws, size_t ws_size,
                              hipStream_t stream) {
    const float* cls = (const float*)d_in[0];
    const float* reg = (const float*)d_in[1];
    const float* anc = (const float*)d_in[2];
    const int*   ph  = (const int*)d_in[3];
    const int*   pw  = (const int*)d_in[4];

    int A = in_sizes[2] / 4;
    int C = in_sizes[0] / A;

    float* out       = (float*)d_out;
    float* out_boxes = out + (size_t)2 * A;

    // workspace layout: akey | overflow | segcnt | gbuf
    size_t akey_bytes = (size_t)A * sizeof(u64);
    size_t off_of     = (akey_bytes + 255) & ~(size_t)255;
    size_t off_sc     = (off_of + 256 + 255) & ~(size_t)255;
    size_t sc_bytes   = (size_t)80 * NBLK * sizeof(u32);
    size_t off_gb     = (off_sc + sc_bytes + 255) & ~(size_t)255;
    size_t gb_bytes   = (size_t)80 * NBLK * SCAP * sizeof(u64);
    size_t need       = off_gb + gb_bytes;

    u64* akey = (u64*)d_ws;

    decode_kernel<<<(A + 255) / 256, 256, 0, stream>>>(anc, reg, ph, pw, out_boxes, akey, A);

    bool fastpath = (C == 80) && ((A & 3) == 0) && (A < (1 << 20)) && (ws_size >= need);
    if (fastpath) {
        u32* overflow = (u32*)((char*)d_ws + off_of);
        u32* segcnt   = (u32*)((char*)d_ws + off_sc);
        u64* gbuf     = (u64*)((char*)d_ws + off_gb);

        hipMemsetAsync(overflow, 0, sizeof(u32), stream);
        scan_collect_kernel<<<NBLK, 256, 0, stream>>>(cls, gbuf, segcnt, overflow, A);
        class_nms_fused_kernel<<<C, 512, 0, stream>>>(segcnt, gbuf, overflow, cls, out_boxes, akey, A, C);
    } else {
        fb_topk_nms_kernel<<<C, 256, 0, stream>>>(cls, out_boxes, akey, A, C);
    }

    finalize_kernel<<<(A + 255) / 256, 256, 0, stream>>>(akey, out, A);
}

// Round 8
// 98.291 us; speedup vs baseline: 11.6847x; 1.7964x over previous
//
#include <hip/hip_runtime.h>
#include <cstdint>

typedef unsigned long long u64;
typedef unsigned int u32;

#define CLS_T    0.05f
#define T0G      0.98f      // collect threshold (pass 1)
#define T1G      0.9965f    // candidate filter threshold (pass 2)
#define TOPK     300
#define NWORDS   5          // ceil(300/64)
#define HBINS    2560
#define KEY_BASE 0x3D000000u
#define CCAP     1024
#define NBLK     2048       // scan blocks
#define SCAP     24         // slots per (class, scan-block)
#define DCAP     8192       // dense per-class capacity

__device__ inline u32 bin_of_bits(u32 bits) {
    u32 b = (bits - KEY_BASE) >> 14;
    if (b > (HBINS - 1)) b = HBINS - 1;
    return b;
}

// compare-exchange for register bitonic: keep max if (lo==up), else min
__device__ inline void cex(u64& v, u64 p, bool lo, bool up) {
    u64 mx = v > p ? v : p;
    u64 mn = v > p ? p : v;
    v = (lo == up) ? mx : mn;
}
__device__ inline void sstep(u64& a0, u64& a1, u32 tid, u32 kk, u32 j) {
    u64 p0 = __shfl_xor((unsigned long long)a0, (int)j, 64);
    u64 p1 = __shfl_xor((unsigned long long)a1, (int)j, 64);
    bool lo = ((tid & j) == 0);
    cex(a0, p0, lo, ((tid & kk) == 0));
    cex(a1, p1, lo, (((tid + 512u) & kk) == 0));
}
__device__ inline void lstep(u64* cand, u64& a0, u64& a1, u32 tid, u32 kk, u32 j) {
    __syncthreads();
    cand[tid] = a0; cand[tid + 512] = a1;
    __syncthreads();
    u64 p0 = cand[tid ^ j], p1 = cand[(tid ^ j) + 512];
    bool lo = ((tid & j) == 0);
    cex(a0, p0, lo, ((tid & kk) == 0));
    cex(a1, p1, lo, (((tid + 512u) & kk) == 0));
}

// ---------------- decode boxes (+clip) + zero akey ----------------
__global__ void decode_kernel(const float* __restrict__ anc,
                              const float* __restrict__ reg,
                              const int* __restrict__ ph,
                              const int* __restrict__ pw,
                              float* __restrict__ boxes,
                              u64* __restrict__ akey, int A)
{
    int a = blockIdx.x * blockDim.x + threadIdx.x;
    if (a >= A) return;
    akey[a] = 0;
    float x1 = anc[a*4+0], y1 = anc[a*4+1], x2 = anc[a*4+2], y2 = anc[a*4+3];
    float w = x2 - x1, h = y2 - y1;
    float cx = x1 + 0.5f*w, cy = y1 + 0.5f*h;
    float r0 = reg[a*4+0]*0.1f, r1 = reg[a*4+1]*0.1f;
    float r2 = reg[a*4+2]*0.2f, r3 = reg[a*4+3]*0.2f;
    float pcx = cx + r0*w, pcy = cy + r1*h;
    float pw_ = expf(r2)*w, ph_ = expf(r3)*h;
    float W = (float)(*pw), H = (float)(*ph);
    boxes[a*4+0] = fmaxf(pcx - 0.5f*pw_, 0.0f);
    boxes[a*4+1] = fmaxf(pcy - 0.5f*ph_, 0.0f);
    boxes[a*4+2] = fminf(pcx + 0.5f*pw_, W);
    boxes[a*4+3] = fminf(pcy + 0.5f*ph_, H);
}

// ---------------- one coalesced pass: collect s > T0G, zero global atomics ----------------
__global__ __launch_bounds__(256) void scan_collect_kernel(
    const float* __restrict__ cls,
    u64* __restrict__ gbuf, u32* __restrict__ segcnt,
    u32* __restrict__ overflow, int A)
{
    __shared__ u32 cnt[80];
    __shared__ u64 buf[80][SCAP];
    __shared__ u32 s_over;
    const int tid = threadIdx.x;
    const int blk = blockIdx.x;

    for (int i = tid; i < 80; i += 256) cnt[i] = 0;
    if (tid == 0) s_over = 0;
    __syncthreads();

    size_t Nf4 = (size_t)A * 20;   // A*80/4
    const float4* p4 = (const float4*)cls;
    for (size_t i = (size_t)blk * 256 + tid; i < Nf4; i += (size_t)NBLK * 256) {
        float4 v = p4[i];
        float ss[4] = {v.x, v.y, v.z, v.w};
        #pragma unroll
        for (int q = 0; q < 4; ++q) {
            if (ss[q] > T0G) {
                u32 flat = (u32)(i * 4 + q);
                u32 a = flat / 80u;            // const-div -> magic mul
                u32 c = flat - a * 80u;
                u32 p = atomicAdd(&cnt[c], 1u);   // LDS atomic only
                if (p < SCAP) buf[c][p] = ((u64)__float_as_uint(ss[q]) << 32) | (u32)(~a);
                else s_over = 1;
            }
        }
    }
    __syncthreads();

    for (int m = tid; m < 80 * SCAP; m += 256) {
        int c = m / SCAP, e = m - c * SCAP;
        u32 cc = cnt[c]; if (cc > SCAP) cc = SCAP;
        if ((u32)e < cc)
            gbuf[((size_t)c * NBLK + blk) * SCAP + e] = buf[c][e];
    }
    for (int c = tid; c < 80; c += 256) {
        u32 cc = cnt[c]; if (cc > SCAP) cc = SCAP;
        segcnt[(size_t)c * NBLK + blk] = cc;
    }
    if (tid == 0 && s_over) *overflow = 1;
}

// ---------------- per-class exclusive prefix over segcnt + totals ----------------
__global__ __launch_bounds__(256) void prefix_kernel(
    const u32* __restrict__ segcnt, u32* __restrict__ pref,
    u32* __restrict__ totals)
{
    const int c = blockIdx.x;
    const int tid = threadIdx.x;
    __shared__ u32 part[256];

    const u32* row = segcnt + (size_t)c * NBLK;
    u32 v[8];
    u32 s = 0;
    #pragma unroll
    for (int q = 0; q < 8; ++q) { v[q] = row[tid * 8 + q]; s += v[q]; }
    part[tid] = s;
    __syncthreads();
    // Hillis-Steele inclusive scan
    for (int d = 1; d < 256; d <<= 1) {
        u32 t = (tid >= d) ? part[tid - d] : 0;
        __syncthreads();
        part[tid] += t;
        __syncthreads();
    }
    u32 running = part[tid] - s;     // exclusive base for this thread's chunk
    u32* prow = pref + (size_t)c * NBLK;
    #pragma unroll
    for (int q = 0; q < 8; ++q) { prow[tid * 8 + q] = running; running += v[q]; }
    if (tid == 255) totals[c] = part[255];
}

// ---------------- compact: scatter (class,block) slots to dense rows ----------------
__global__ __launch_bounds__(256) void compact_kernel(
    const u32* __restrict__ segcnt, const u32* __restrict__ pref,
    const u64* __restrict__ gbuf, u64* __restrict__ gbuf2)
{
    const int b = blockIdx.x;
    const int tid = threadIdx.x;
    __shared__ u32 scnt[80], sbase[80];
    for (int c = tid; c < 80; c += 256) {
        scnt[c]  = segcnt[(size_t)c * NBLK + b];
        sbase[c] = pref[(size_t)c * NBLK + b];
    }
    __syncthreads();
    for (int m = tid; m < 80 * SCAP; m += 256) {
        int c = m / SCAP, e = m - c * SCAP;
        if ((u32)e < scnt[c]) {
            u32 p = sbase[c] + (u32)e;
            if (p < DCAP)
                gbuf2[(size_t)c * DCAP + p] = gbuf[((size_t)c * NBLK + b) * SCAP + e];
        }
    }
}

// ---------------- per-class: dense gather + sort + NMS + scatter ----------------
__global__ __launch_bounds__(512) void class_nms_fused_kernel(
    const u32* __restrict__ totals, const u64* __restrict__ gbuf2,
    const u32* __restrict__ overflow,
    const float* __restrict__ cls,     // [A][C] for slow path
    const float* __restrict__ boxes, u64* __restrict__ akey, int A, int C)
{
    const int c = blockIdx.x;
    const u32 tid = threadIdx.x;
    const int lane = tid & 63;
    const int wv = tid >> 6;

    __shared__ u32 sh[HBINS];          // slow path histogram
    __shared__ u64 cand[CCAP];
    __shared__ u32 s_sel, s_cnt, s_rem;
    __shared__ float bx1[TOPK], by1[TOPK], bx2[TOPK], by2[TOPK], bar[TOPK];
    __shared__ u64 s_alive[NWORDS], s_newalive[NWORDS];
    __shared__ u32 s_changed;

    if (tid == 0) { s_sel = 0; s_cnt = 0; s_changed = 0; }
    __syncthreads();

    const bool over = (*overflow != 0);
    const u32 n = totals[c];
    u32 cnt_f = 0;
    bool fast_ok = false;

    if (!over && n >= TOPK && n <= DCAP) {
        const u64* src = gbuf2 + (size_t)c * DCAP;
        const u32 T1 = __float_as_uint(T1G);
        for (u32 i = tid; i < n; i += 512) {
            u64 e = src[i];
            bool take = ((u32)(e >> 32) > T1);
            u64 m = __ballot(take);
            int nW = __popcll(m);
            if (nW) {
                int ldr = __ffsll((unsigned long long)m) - 1;
                u32 base = 0;
                if (lane == ldr) base = atomicAdd(&s_cnt, (u32)nW);
                base = __shfl(base, ldr);
                if (take) {
                    u32 p = base + (u32)__popcll(m & ((1ull << lane) - 1ull));
                    if (p < CCAP) cand[p] = e;
                }
            }
        }
        __syncthreads();
        cnt_f = s_cnt;
        fast_ok = (cnt_f >= TOPK && cnt_f <= CCAP);
    }

    if (!fast_ok) {
        // ---- slow exact path: 2-level select over the class column ----
        __syncthreads();
        for (int i = tid; i < HBINS; i += 512) sh[i] = 0;
        if (tid == 0) s_cnt = 0;
        __syncthreads();
        for (int a = tid; a < A; a += 512) {
            float s = cls[(size_t)a * C + c];
            if (s > CLS_T) atomicAdd(&sh[bin_of_bits(__float_as_uint(s))], 1u);
        }
        __syncthreads();
        if (tid == 0) {
            u32 cum = 0; int sel = 0;
            for (int d = HBINS - 1; d >= 0; --d) {
                u32 nc = cum + sh[d];
                if (nc >= TOPK) { sel = d; break; }
                cum = nc;
            }
            s_sel = (u32)sel; s_rem = TOPK - cum;
        }
        __syncthreads();
        const u32 sel1 = s_sel;
        __syncthreads();
        for (int i = tid; i < 256; i += 512) sh[i] = 0;
        __syncthreads();
        for (int a = tid; a < A; a += 512) {
            float s = cls[(size_t)a * C + c];
            if (s > CLS_T) {
                u32 k = __float_as_uint(s) - KEY_BASE;
                u32 b = k >> 14; if (b >= HBINS) b = HBINS - 1;
                if (b == sel1) atomicAdd(&sh[(k >> 6) & 0xFF], 1u);
            }
        }
        __syncthreads();
        if (tid == 0) {
            u32 rem = s_rem, cum = 0; int sel = 0;
            for (int d = 255; d >= 0; --d) {
                u32 nc = cum + sh[d];
                if (nc >= rem) { sel = d; break; }
                cum = nc;
            }
            s_sel = (sel1 << 14) | ((u32)sel << 6);
            s_cnt = 0;
        }
        __syncthreads();
        const u32 thresh = s_sel;
        for (int a = tid; a < A; a += 512) {
            float s = cls[(size_t)a * C + c];
            if (s > CLS_T) {
                u32 bits = __float_as_uint(s);
                if (bits - KEY_BASE >= thresh) {
                    u32 p = atomicAdd(&s_cnt, 1u);
                    if (p < CCAP) cand[p] = ((u64)bits << 32) | (u32)(~(u32)a);
                }
            }
        }
        __syncthreads();
        cnt_f = s_cnt < CCAP ? s_cnt : CCAP;
    }

    // ---- pad + register bitonic sort of 1024 (2 elems/thread), descending ----
    for (u32 i = cnt_f + tid; i < CCAP; i += 512) cand[i] = 0;
    __syncthreads();
    u64 a0 = cand[tid], a1 = cand[tid + 512];
    for (u32 kk = 2; kk <= 64; kk <<= 1)
        for (u32 j = kk >> 1; j >= 1; j >>= 1)
            sstep(a0, a1, tid, kk, j);
    lstep(cand, a0, a1, tid, 128u, 64u);
    for (u32 j = 32; j >= 1; j >>= 1) sstep(a0, a1, tid, 128u, j);
    lstep(cand, a0, a1, tid, 256u, 128u);
    lstep(cand, a0, a1, tid, 256u, 64u);
    for (u32 j = 32; j >= 1; j >>= 1) sstep(a0, a1, tid, 256u, j);
    lstep(cand, a0, a1, tid, 512u, 256u);
    lstep(cand, a0, a1, tid, 512u, 128u);
    lstep(cand, a0, a1, tid, 512u, 64u);
    for (u32 j = 32; j >= 1; j >>= 1) sstep(a0, a1, tid, 512u, j);
    {   // kk=1024, j=512: in-thread exchange (up = true for tid<512)
        u64 mx = a0 > a1 ? a0 : a1, mn = a0 > a1 ? a1 : a0;
        a0 = mx; a1 = mn;
    }
    lstep(cand, a0, a1, tid, 1024u, 256u);
    lstep(cand, a0, a1, tid, 1024u, 128u);
    lstep(cand, a0, a1, tid, 1024u, 64u);
    for (u32 j = 32; j >= 1; j >>= 1) sstep(a0, a1, tid, 1024u, j);
    // thread tid holds sorted element tid in a0

    const int T = (int)(cnt_f < TOPK ? cnt_f : TOPK);

    // ---- boxes for my candidate ----
    u64 key = a0; u32 aidx = 0;
    float x1 = 0, y1 = 0, x2 = 0, y2 = 0, ar = 0;
    if ((int)tid < T) {
        aidx = ~(u32)(key & 0xFFFFFFFFull);
        float4 b4 = *(const float4*)(boxes + (size_t)aidx * 4);
        x1 = b4.x; y1 = b4.y; x2 = b4.z; y2 = b4.w;
        ar = fmaxf(x2 - x1, 0.0f) * fmaxf(y2 - y1, 0.0f);
        bx1[tid] = x1; by1[tid] = y1; bx2[tid] = x2; by2[tid] = y2; bar[tid] = ar;
    }
    if (tid < NWORDS) {
        int rem = T - (int)tid * 64;
        s_alive[tid] = rem >= 64 ? ~0ull : (rem > 0 ? ((1ull << rem) - 1ull) : 0ull);
    }
    __syncthreads();

    // colmask: which i<tid suppress me (IoU>0.5), in registers
    u64 cm[NWORDS] = {0,0,0,0,0};
    if ((int)tid < T) {
        for (int i = 0; i < (int)tid; ++i) {
            float iw = fmaxf(fminf(x2, bx2[i]) - fmaxf(x1, bx1[i]), 0.0f);
            float ih = fmaxf(fminf(y2, by2[i]) - fmaxf(y1, by1[i]), 0.0f);
            float inter = iw * ih;
            float uni = ((ar + bar[i]) - inter) + 1e-8f;
            float q = inter - 0.5f * uni;
            bool sup;
            if (fabsf(q) > 1e-5f * uni) sup = (q > 0.0f);
            else sup = (inter / uni > 0.5f);
            if (sup) cm[i >> 6] |= 1ull << (i & 63);
        }
    }

    // synchronous fixpoint == greedy keep set
    for (int round = 0; round < TOPK; ++round) {
        u64 al[NWORDS];
        #pragma unroll
        for (int k2 = 0; k2 < NWORDS; ++k2) al[k2] = s_alive[k2];
        bool alive_t = false;
        if ((int)tid < T) {
            u64 any = 0;
            #pragma unroll
            for (int k2 = 0; k2 < NWORDS; ++k2) any |= (al[k2] & cm[k2]);
            alive_t = (any == 0);
        }
        u64 w = __ballot(alive_t);
        if (wv < NWORDS && lane == 0) {
            s_newalive[wv] = w;
            if (w != al[wv]) s_changed = 1;
        }
        __syncthreads();
        u32 ch = s_changed;
        __syncthreads();
        if (!ch) break;
        if (tid < NWORDS) s_alive[tid] = s_newalive[tid];
        if (tid == 0) s_changed = 0;
        __syncthreads();
    }

    if ((int)tid < T) {
        if ((s_alive[tid >> 6] >> (tid & 63)) & 1ull) {
            u32 sbits = (u32)(key >> 32);
            u64 outk = ((u64)sbits << 32) | (u32)(255 - c);
            atomicMax(&akey[aidx], outk);
        }
    }
}

// ---------------- finalize ----------------
__global__ void finalize_kernel(const u64* __restrict__ akey,
                                float* __restrict__ out, int A)
{
    int a = blockIdx.x * blockDim.x + threadIdx.x;
    if (a >= A) return;
    float* scores = out;
    float* labels = out + A;
    float* boxes  = out + (size_t)2 * A;
    u64 k = akey[a];
    if (k) {
        scores[a] = __uint_as_float((u32)(k >> 32));
        labels[a] = (float)(int)(255u - (u32)(k & 0xFFFFFFFFull));
    } else {
        scores[a] = 0.0f;
        labels[a] = -1.0f;
        boxes[(size_t)a*4+0] = 0.0f;
        boxes[(size_t)a*4+1] = 0.0f;
        boxes[(size_t)a*4+2] = 0.0f;
        boxes[(size_t)a*4+3] = 0.0f;
    }
}

// ---------------- fallback (generic C / small ws): round-1 proven kernel ----------------
#define FB_CAP 1024
__global__ __launch_bounds__(256) void fb_topk_nms_kernel(
    const float* __restrict__ cls,
    const float* __restrict__ boxes,
    u64* __restrict__ akey,
    int A, int C)
{
    const int c   = blockIdx.x;
    const int tid = threadIdx.x;

    __shared__ u32 hist[HBINS];
    __shared__ u64 cand[FB_CAP];
    __shared__ float bx1[TOPK], by1[TOPK], bx2[TOPK], by2[TOPK], bar[TOPK];
    __shared__ u64 iomask[TOPK][NWORDS];
    __shared__ u64 keepm[NWORDS];
    __shared__ u32 s_sel1, s_sel2, s_rem, s_cnt;

    for (int i = tid; i < HBINS; i += 256) hist[i] = 0;
    __syncthreads();
    for (int a = tid; a < A; a += 256) {
        float s = cls[(size_t)a * C + c];
        if (s > CLS_T) {
            u32 k = __float_as_uint(s) - KEY_BASE;
            u32 b = k >> 14; if (b >= HBINS) b = HBINS - 1;
            atomicAdd(&hist[b], 1u);
        }
    }
    __syncthreads();
    if (tid == 0) {
        u32 cum = 0; int sel = 0;
        for (int d = HBINS - 1; d >= 0; --d) {
            u32 nc = cum + hist[d];
            if (nc >= TOPK) { sel = d; break; }
            cum = nc;
        }
        s_sel1 = (u32)sel; s_rem = TOPK - cum;
    }
    __syncthreads();
    const u32 sel1 = s_sel1;

    for (int i = tid; i < 256; i += 256) hist[i] = 0;
    __syncthreads();
    for (int a = tid; a < A; a += 256) {
        float s = cls[(size_t)a * C + c];
        if (s > CLS_T) {
            u32 k = __float_as_uint(s) - KEY_BASE;
            u32 b = k >> 14; if (b >= HBINS) b = HBINS - 1;
            if (b == sel1) atomicAdd(&hist[(k >> 6) & 0xFF], 1u);
        }
    }
    __syncthreads();
    if (tid == 0) {
        u32 rem = s_rem, cum = 0; int sel = 0;
        for (int d = 255; d >= 0; --d) {
            u32 nc = cum + hist[d];
            if (nc >= rem) { sel = d; break; }
            cum = nc;
        }
        s_sel2 = (u32)sel; s_cnt = 0;
    }
    __syncthreads();
    const u32 thresh = (sel1 << 14) | (s_sel2 << 6);

    for (int a = tid; a < A; a += 256) {
        float s = cls[(size_t)a * C + c];
        if (s > CLS_T) {
            u32 bits = __float_as_uint(s);
            u32 k = bits - KEY_BASE;
            if (k >= thresh) {
                u32 pos = atomicAdd(&s_cnt, 1u);
                if (pos < FB_CAP) cand[pos] = ((u64)bits << 32) | (u32)(~(u32)a);
            }
        }
    }
    __syncthreads();
    const u32 total = s_cnt < FB_CAP ? s_cnt : FB_CAP;
    for (int i = tid; i < FB_CAP; i += 256)
        if (i >= (int)total) cand[i] = 0;
    __syncthreads();

    for (u32 kk = 2; kk <= FB_CAP; kk <<= 1) {
        for (u32 j = kk >> 1; j > 0; j >>= 1) {
            for (u32 i = tid; i < FB_CAP; i += 256) {
                u32 l = i ^ j;
                if (l > i) {
                    u64 av = cand[i], bv = cand[l];
                    bool up = ((i & kk) == 0);
                    if ((up && av < bv) || (!up && av > bv)) { cand[i] = bv; cand[l] = av; }
                }
            }
            __syncthreads();
        }
    }
    const int T = (int)(total < TOPK ? total : TOPK);

    for (int i = tid; i < T; i += 256) {
        u32 a = ~(u32)(cand[i] & 0xFFFFFFFFull);
        float x1 = boxes[(size_t)a*4+0], y1 = boxes[(size_t)a*4+1];
        float x2 = boxes[(size_t)a*4+2], y2 = boxes[(size_t)a*4+3];
        bx1[i] = x1; by1[i] = y1; bx2[i] = x2; by2[i] = y2;
        bar[i] = fmaxf(x2 - x1, 0.0f) * fmaxf(y2 - y1, 0.0f);
    }
    __syncthreads();

    for (int i = tid; i < T; i += 256) {
        u64 m[NWORDS] = {0,0,0,0,0};
        float x1 = bx1[i], y1 = by1[i], x2 = bx2[i], y2 = by2[i], ai = bar[i];
        for (int j = i + 1; j < T; ++j) {
            float iw = fmaxf(fminf(x2, bx2[j]) - fmaxf(x1, bx1[j]), 0.0f);
            float ih = fmaxf(fminf(y2, by2[j]) - fmaxf(y1, by1[j]), 0.0f);
            float inter = iw * ih;
            float uni = ((ai + bar[j]) - inter) + 1e-8f;
            if (inter / uni > 0.5f) m[j >> 6] |= 1ull << (j & 63);
        }
        for (int k2 = 0; k2 < NWORDS; ++k2) iomask[i][k2] = m[k2];
    }
    __syncthreads();

    if (tid == 0) {
        u64 sup[NWORDS] = {0,0,0,0,0};
        u64 kp [NWORDS] = {0,0,0,0,0};
        for (int i = 0; i < T; ++i) {
            if (!((sup[i >> 6] >> (i & 63)) & 1ull)) {
                kp[i >> 6] |= 1ull << (i & 63);
                for (int k2 = 0; k2 < NWORDS; ++k2) sup[k2] |= iomask[i][k2];
            }
        }
        for (int k2 = 0; k2 < NWORDS; ++k2) keepm[k2] = kp[k2];
    }
    __syncthreads();

    for (int i = tid; i < T; i += 256) {
        if ((keepm[i >> 6] >> (i & 63)) & 1ull) {
            u64 key = cand[i];
            u32 a = ~(u32)(key & 0xFFFFFFFFull);
            u32 sbits = (u32)(key >> 32);
            u64 outk = ((u64)sbits << 32) | (u32)(255 - c);
            atomicMax(&akey[a], outk);
        }
    }
}

extern "C" void kernel_launch(void* const* d_in, const int* in_sizes, int n_in,
                              void* d_out, int out_size, void* d_ws, size_t ws_size,
                              hipStream_t stream) {
    const float* cls = (const float*)d_in[0];
    const float* reg = (const float*)d_in[1];
    const float* anc = (const float*)d_in[2];
    const int*   ph  = (const int*)d_in[3];
    const int*   pw  = (const int*)d_in[4];

    int A = in_sizes[2] / 4;
    int C = in_sizes[0] / A;

    float* out       = (float*)d_out;
    float* out_boxes = out + (size_t)2 * A;

    // workspace: akey | overflow | segcnt | pref | totals | gbuf | gbuf2
    size_t akey_bytes = (size_t)A * sizeof(u64);
    size_t off_of     = (akey_bytes + 255) & ~(size_t)255;
    size_t off_sc     = (off_of + 256 + 255) & ~(size_t)255;
    size_t sc_bytes   = (size_t)80 * NBLK * sizeof(u32);
    size_t off_pf     = (off_sc + sc_bytes + 255) & ~(size_t)255;
    size_t off_tt     = (off_pf + sc_bytes + 255) & ~(size_t)255;
    size_t tt_bytes   = 80 * sizeof(u32);
    size_t off_gb     = (off_tt + tt_bytes + 255) & ~(size_t)255;
    size_t gb_bytes   = (size_t)80 * NBLK * SCAP * sizeof(u64);
    size_t off_g2     = (off_gb + gb_bytes + 255) & ~(size_t)255;
    size_t g2_bytes   = (size_t)80 * DCAP * sizeof(u64);
    size_t need       = off_g2 + g2_bytes;

    u64* akey = (u64*)d_ws;

    decode_kernel<<<(A + 255) / 256, 256, 0, stream>>>(anc, reg, ph, pw, out_boxes, akey, A);

    bool fastpath = (C == 80) && ((A & 3) == 0) && (A < (1 << 20)) && (ws_size >= need);
    if (fastpath) {
        u32* overflow = (u32*)((char*)d_ws + off_of);
        u32* segcnt   = (u32*)((char*)d_ws + off_sc);
        u32* pref     = (u32*)((char*)d_ws + off_pf);
        u32* totals   = (u32*)((char*)d_ws + off_tt);
        u64* gbuf     = (u64*)((char*)d_ws + off_gb);
        u64* gbuf2    = (u64*)((char*)d_ws + off_g2);

        hipMemsetAsync(overflow, 0, sizeof(u32), stream);
        scan_collect_kernel<<<NBLK, 256, 0, stream>>>(cls, gbuf, segcnt, overflow, A);
        prefix_kernel<<<80, 256, 0, stream>>>(segcnt, pref, totals);
        compact_kernel<<<NBLK, 256, 0, stream>>>(segcnt, pref, gbuf, gbuf2);
        class_nms_fused_kernel<<<C, 512, 0, stream>>>(totals, gbuf2, overflow, cls, out_boxes, akey, A, C);
    } else {
        fb_topk_nms_kernel<<<C, 256, 0, stream>>>(cls, out_boxes, akey, A, C);
    }

    finalize_kernel<<<(A + 255) / 256, 256, 0, stream>>>(akey, out, A);
}